// Round 7
// baseline (1937.970 us; speedup 1.0000x reference)
//
#include <hip/hip_runtime.h>

// Model dims
#define T_ 64
#define B_ 1024
#define V_ 128
#define H_ 512

typedef short bf16x8 __attribute__((ext_vector_type(8)));
typedef float f32x4 __attribute__((ext_vector_type(4)));

__device__ __forceinline__ unsigned short f2bf(float f) {
    union { float f; unsigned int i; } v; v.f = f;
    unsigned int x = v.i;
    return (unsigned short)((x + 0x7FFFu + ((x >> 16) & 1u)) >> 16);
}
__device__ __forceinline__ float bf2f(unsigned short u) {
    union { unsigned int i; float f; } v; v.i = ((unsigned int)u) << 16; return v.f;
}
__device__ __forceinline__ float sigm(float x) { return 1.f / (1.f + __expf(-x)); }
__device__ __forceinline__ float tanh_fast(float x) {
    float ax = fabsf(x);
    float t = 1.f - 2.f / (__expf(2.f * ax) + 1.f);   // saturates to 1 on overflow
    return copysignf(t, x);
}
// device-visible store of one bf16, write-through to MALL, no cache flush
__device__ __forceinline__ void store_bf16_wt(unsigned short* p, unsigned short v) {
    unsigned int vv = v;
    asm volatile("global_store_short %0, %1, off sc0 sc1" :: "v"(p), "v"(vv) : "memory");
}

// ---------------- cbias = xh_b + hh_b; zero barrier counters ----------------
__global__ __launch_bounds__(256) void cbias_k(const float* __restrict__ xh_b,
                                               const float* __restrict__ hh_b,
                                               float* __restrict__ cbias,
                                               unsigned int* __restrict__ ctr) {
    int i = blockIdx.x * 256 + threadIdx.x;          // 2048
    cbias[i] = xh_b[i] + hh_b[i];
    if (i < 512) ctr[i] = 0u;                        // 8 counters, 256B apart
}

// ---------------- convert inp fp32 -> bf16 ----------------
__global__ __launch_bounds__(256) void convx_k(const float* __restrict__ x,
                                               unsigned short* __restrict__ xbf) {
    int i = blockIdx.x * 256 + threadIdx.x;          // T*B*V = 8388608
    xbf[i] = f2bf(x[i]);
}

// ---------------- build Wt bf16 [2048][640]: Wt[n][k] = W[k][n] ----------------
__global__ __launch_bounds__(256) void convw_k(const float* __restrict__ xw,
                                               const float* __restrict__ hw,
                                               unsigned short* __restrict__ wt) {
    int i = blockIdx.x * 256 + threadIdx.x;          // 2048*640 = 1310720
    int n = i / 640, k = i - n * 640;
    float v = (k < 128) ? xw[k * 2048 + n] : hw[(k - 128) * 2048 + n];
    wt[i] = f2bf(v);
}

// ---------------- build Wo bf16 [128][512]: Wo[n][k] = out_w[k][n] ----------------
__global__ __launch_bounds__(256) void convow_k(const float* __restrict__ ow,
                                                unsigned short* __restrict__ wo) {
    int i = blockIdx.x * 256 + threadIdx.x;          // 128*512 = 65536
    int n = i >> 9, k = i & 511;
    wo[i] = f2bf(ow[k * 128 + n]);
}

// ---------------- conv1 3x3 pad1 + relu + 2x2 maxpool ----------------
__global__ __launch_bounds__(256) void conv1_k(const float* __restrict__ img,
                                               const float* __restrict__ w,
                                               const float* __restrict__ bias,
                                               float* __restrict__ out) {
    int id = blockIdx.x * 256 + threadIdx.x;         // B*8*32*32 = 8388608
    int px = id & 31, py = (id >> 5) & 31, oc = (id >> 10) & 7, b = id >> 13;
    const float* ip = img + b * 4096;
    float wv[9];
#pragma unroll
    for (int t = 0; t < 9; ++t) wv[t] = w[oc * 9 + t];
    float bs = bias[oc];
    float m = -3.4e38f;
#pragma unroll
    for (int sy = 0; sy < 2; ++sy)
#pragma unroll
    for (int sx = 0; sx < 2; ++sx) {
        int oy = 2 * py + sy, ox = 2 * px + sx;
        float acc = bs;
#pragma unroll
        for (int ky = 0; ky < 3; ++ky) {
            int iy = oy + ky - 1;
            if (iy < 0 || iy > 63) continue;
#pragma unroll
            for (int kx = 0; kx < 3; ++kx) {
                int ix = ox + kx - 1;
                if (ix < 0 || ix > 63) continue;
                acc += ip[iy * 64 + ix] * wv[ky * 3 + kx];
            }
        }
        m = fmaxf(m, acc);
    }
    out[id] = fmaxf(m, 0.f);
}

// ---------------- conv2 5x5 pad1 + relu + 2x2 maxpool ----------------
__device__ __forceinline__ int c2idx(int ic, int y, int x) {
    return ((ic * 34 + y) * 2 + (x & 1)) * 18 + (x >> 1);
}
__global__ __launch_bounds__(256) void conv2_k(const float* __restrict__ in,
                                               const float* __restrict__ w,
                                               const float* __restrict__ bias,
                                               float* __restrict__ feat) {
    __shared__ float in_s[8 * 34 * 36];
    __shared__ float w_s[3200];
    __shared__ float b_s[16];
    int tid = threadIdx.x, b = blockIdx.x;
    for (int e = tid; e < 8 * 34 * 34; e += 256) {
        int ic = e / 1156, r = e - ic * 1156;
        int y = r / 34, xx = r - y * 34;
        float v = 0.f;
        if (y >= 1 && y <= 32 && xx >= 1 && xx <= 32)
            v = in[b * 8192 + ic * 1024 + (y - 1) * 32 + (xx - 1)];
        in_s[c2idx(ic, y, xx)] = v;
    }
    for (int e = tid; e < 3200; e += 256) w_s[e] = w[e];
    if (tid < 16) b_s[tid] = bias[tid];
    __syncthreads();
    for (int o = tid; o < 3600; o += 256) {
        int oc = o / 225, p = o - oc * 225;
        int py = p / 15, px = p - py * 15;
        float a00, a01, a10, a11;
        a00 = a01 = a10 = a11 = b_s[oc];
        for (int ic = 0; ic < 8; ++ic) {
            const float* wp = w_s + (oc * 8 + ic) * 25;
#pragma unroll
            for (int ky = 0; ky < 5; ++ky) {
                int y0 = 2 * py + ky;
                float r0[6], r1[6];
#pragma unroll
                for (int xx = 0; xx < 6; ++xx) {
                    r0[xx] = in_s[c2idx(ic, y0,     2 * px + xx)];
                    r1[xx] = in_s[c2idx(ic, y0 + 1, 2 * px + xx)];
                }
#pragma unroll
                for (int kx = 0; kx < 5; ++kx) {
                    float wv = wp[ky * 5 + kx];
                    a00 += r0[kx    ] * wv;
                    a01 += r0[kx + 1] * wv;
                    a10 += r1[kx    ] * wv;
                    a11 += r1[kx + 1] * wv;
                }
            }
        }
        float mx = fmaxf(fmaxf(a00, a01), fmaxf(a10, a11));
        feat[b * 3600 + o] = fmaxf(mx, 0.f);
    }
}

// ---------------- imgfc: e = relu(feat @ W + b), M=1024 N=512 K=3600 ----------------
__global__ __launch_bounds__(256) void imgfc_gemm(const float* __restrict__ A,
                                                  const float* __restrict__ W,
                                                  const float* __restrict__ bias,
                                                  float* __restrict__ E) {
    __shared__ __align__(16) float As[16][68];
    __shared__ __align__(16) float Bs[16][68];
    const int tid = threadIdx.x;
    const int tx = tid & 15, ty = tid >> 4;
    const int row0 = blockIdx.y * 64, col0 = blockIdx.x * 64;
    const int am = tid >> 2, ak = (tid & 3) * 4;
    const int bk = tid >> 4, bn = (tid & 15) * 4;
    float acc[4][4] = {};
    for (int k0 = 0; k0 < 3600; k0 += 16) {
        float4 fa = *(const float4*)(A + (row0 + am) * 3600 + k0 + ak);
        float4 fb = *(const float4*)(W + (k0 + bk) * 512 + col0 + bn);
        __syncthreads();
        As[ak + 0][am] = fa.x; As[ak + 1][am] = fa.y; As[ak + 2][am] = fa.z; As[ak + 3][am] = fa.w;
        Bs[bk][bn + 0] = fb.x; Bs[bk][bn + 1] = fb.y; Bs[bk][bn + 2] = fb.z; Bs[bk][bn + 3] = fb.w;
        __syncthreads();
#pragma unroll
        for (int kk = 0; kk < 16; ++kk) {
            float4 av = *(const float4*)(&As[kk][ty * 4]);
            float4 bv = *(const float4*)(&Bs[kk][tx * 4]);
            float a[4] = {av.x, av.y, av.z, av.w};
            float bb[4] = {bv.x, bv.y, bv.z, bv.w};
#pragma unroll
            for (int i = 0; i < 4; ++i)
#pragma unroll
            for (int j = 0; j < 4; ++j) acc[i][j] += a[i] * bb[j];
        }
    }
#pragma unroll
    for (int i = 0; i < 4; ++i) {
        int r = row0 + ty * 4 + i;
#pragma unroll
        for (int j = 0; j < 4; ++j) {
            int cI = col0 + tx * 4 + j;
            E[r * 512 + cI] = fmaxf(acc[i][j] + bias[cI], 0.f);
        }
    }
}

#define MFMA16(a, b, c) __builtin_amdgcn_mfma_f32_16x16x32_bf16((a), (b), (c), 0, 0, 0)

// ---------------- persistent LSTM: all 64 steps in one dispatch ----------------
// 256 blocks x 512 threads (8 waves, 2/SIMD). Block = (rg, jblk): 128 rows x
// 16 cols x 4 gates. Wave = (row-pair rt2, gate-pair gp): 2x16 rows, 2 gates;
// its B-slice (2x20 frags = 160 VGPRs) is register-resident for all 64 steps.
// gp0 holds gates i,f + the c-state; gp1 computes g,o and passes raw
// pre-activations via a 16 KB LDS exchange (one __syncthreads per step).
// Sync across blocks: sc0/sc1 write-through hs stores + per-rg padded counter,
// relaxed agent atomics, per-wave arrive/poll. No fences -> L2 stays warm.
__global__ __launch_bounds__(512, 2) void lstm_persist(
        const unsigned short* __restrict__ xbf,   // [T,B,128] bf16
        const unsigned short* __restrict__ wt,    // [2048,640] bf16
        const float* __restrict__ cbias,          // [2048]
        const float* __restrict__ eimg,           // [B,512]
        unsigned short* __restrict__ hs,          // [T,B,512] bf16
        unsigned int* __restrict__ ctr) {         // [8*64], 256B stride
    __shared__ float ex_s[128 * 16 * 2];          // (g,o) exchange, 16 KB
    const int tid = threadIdx.x;
    const int wave = tid >> 6, lane = tid & 63;
    const int quad = lane >> 4, l16 = lane & 15;
    const int rt2 = wave & 3, gp = wave >> 2;
    const int jblk = blockIdx.x & 31;
    const int rg = blockIdx.x >> 5;
    const int j0 = jblk * 16;
    const int rowbase = rg * 128 + rt2 * 32;      // two 16-row tiles: +0, +16
    unsigned int* myctr = ctr + rg * 64;

    // B-fragments for this wave's two gates, all 20 k-chunks (k=0..639)
    bf16x8 bg[2][20];
#pragma unroll
    for (int gg = 0; gg < 2; ++gg) {
        const unsigned short* wrow = wt + (size_t)((gp * 2 + gg) * 512 + j0 + l16) * 640;
#pragma unroll
        for (int kk = 0; kk < 20; ++kk)
            bg[gg][kk] = *(const bf16x8*)(wrow + kk * 32 + quad * 8);
    }
    const int j = j0 + l16;
    float cb[4] = {cbias[j], cbias[512 + j], cbias[1024 + j], cbias[1536 + j]};

    float cst[2][4];
    f32x4 acc[2][2];
#pragma unroll
    for (int tt = 0; tt < 2; ++tt)
#pragma unroll
        for (int gg = 0; gg < 2; ++gg) acc[tt][gg] = (f32x4){0.f, 0.f, 0.f, 0.f};

    // x-part for t=0
#pragma unroll
    for (int kk = 0; kk < 4; ++kk) {
        bf16x8 a0 = *(const bf16x8*)(xbf + (size_t)(rowbase + l16) * 128 + kk * 32 + quad * 8);
        bf16x8 a1 = *(const bf16x8*)(xbf + (size_t)(rowbase + 16 + l16) * 128 + kk * 32 + quad * 8);
        acc[0][0] = MFMA16(a0, bg[0][kk], acc[0][0]);
        acc[0][1] = MFMA16(a0, bg[1][kk], acc[0][1]);
        acc[1][0] = MFMA16(a1, bg[0][kk], acc[1][0]);
        acc[1][1] = MFMA16(a1, bg[1][kk], acc[1][1]);
    }

#pragma unroll 1
    for (int t = 0; t < T_; ++t) {
        if (t > 0) {
            unsigned int target = 128u * (unsigned int)t;   // 32 blocks x 4 gp0 waves per step
            if (lane == 0) {
                int guard = 0;
                while (__hip_atomic_load(myctr, __ATOMIC_RELAXED, __HIP_MEMORY_SCOPE_AGENT) < target
                       && ++guard < (1 << 27))
                    __builtin_amdgcn_s_sleep(2);
            }
            asm volatile("" ::: "memory");
            const unsigned short* hp = hs + (size_t)(t - 1) * (B_ * H_);
#pragma unroll
            for (int kk = 0; kk < 16; ++kk) {
                bf16x8 a0 = *(const bf16x8*)(hp + (size_t)(rowbase + l16) * 512 + kk * 32 + quad * 8);
                bf16x8 a1 = *(const bf16x8*)(hp + (size_t)(rowbase + 16 + l16) * 512 + kk * 32 + quad * 8);
                acc[0][0] = MFMA16(a0, bg[0][4 + kk], acc[0][0]);
                acc[0][1] = MFMA16(a0, bg[1][4 + kk], acc[0][1]);
                acc[1][0] = MFMA16(a1, bg[0][4 + kk], acc[1][0]);
                acc[1][1] = MFMA16(a1, bg[1][4 + kk], acc[1][1]);
            }
        }
        if (gp == 1) {
#pragma unroll
            for (int tt = 0; tt < 2; ++tt)
#pragma unroll
                for (int reg = 0; reg < 4; ++reg) {
                    int rl = rt2 * 32 + tt * 16 + quad * 4 + reg;
                    ex_s[(rl * 16 + l16) * 2 + 0] = acc[tt][0][reg];
                    ex_s[(rl * 16 + l16) * 2 + 1] = acc[tt][1][reg];
                }
        }
        __syncthreads();
        if (gp == 0) {
            unsigned short* ho = hs + (size_t)t * (B_ * H_);
#pragma unroll
            for (int tt = 0; tt < 2; ++tt)
#pragma unroll
                for (int reg = 0; reg < 4; ++reg) {
                    int rl = rt2 * 32 + tt * 16 + quad * 4 + reg;
                    int row = rg * 128 + rl;
                    size_t o = (size_t)row * 512 + j;
                    float ea = (t == 0) ? eimg[o] : 0.f;
                    float iv = sigm(acc[tt][0][reg] + cb[0] + ea);
                    float fv = sigm(acc[tt][1][reg] + cb[1] + ea);
                    float gv = tanh_fast(ex_s[(rl * 16 + l16) * 2 + 0] + cb[2] + ea);
                    float ov = sigm(ex_s[(rl * 16 + l16) * 2 + 1] + cb[3] + ea);
                    float co = (t == 0) ? 0.f : cst[tt][reg];
                    float cn = fv * co + iv * gv;
                    cst[tt][reg] = cn;
                    store_bf16_wt(ho + o, f2bf(ov * tanh_fast(cn)));
                }
            if (t < T_ - 1) {
                asm volatile("s_waitcnt vmcnt(0)" ::: "memory");   // sc1 stores acked
                if (lane == 0)
                    __hip_atomic_fetch_add(myctr, 1u, __ATOMIC_RELAXED, __HIP_MEMORY_SCOPE_AGENT);
            }
        }
        if (t < T_ - 1) {
            // pre-compute x-part(t+1) while other blocks converge on the barrier
#pragma unroll
            for (int tt = 0; tt < 2; ++tt)
#pragma unroll
                for (int gg = 0; gg < 2; ++gg) acc[tt][gg] = (f32x4){0.f, 0.f, 0.f, 0.f};
            const unsigned short* xtp = xbf + (size_t)(t + 1) * (B_ * V_);
#pragma unroll
            for (int kk = 0; kk < 4; ++kk) {
                bf16x8 a0 = *(const bf16x8*)(xtp + (size_t)(rowbase + l16) * 128 + kk * 32 + quad * 8);
                bf16x8 a1 = *(const bf16x8*)(xtp + (size_t)(rowbase + 16 + l16) * 128 + kk * 32 + quad * 8);
                acc[0][0] = MFMA16(a0, bg[0][kk], acc[0][0]);
                acc[0][1] = MFMA16(a0, bg[1][kk], acc[0][1]);
                acc[1][0] = MFMA16(a1, bg[0][kk], acc[1][0]);
                acc[1][1] = MFMA16(a1, bg[1][kk], acc[1][1]);
            }
        }
    }
}

// ---------------- logits + log_softmax via MFMA ----------------
__global__ __launch_bounds__(256, 2) void logits_mfma(
        const unsigned short* __restrict__ hs,    // [65536,512] bf16
        const unsigned short* __restrict__ wo,    // [128][512] bf16, k-major
        const float* __restrict__ ob,             // [128]
        float* __restrict__ out) {                // [65536,128]
    __shared__ unsigned short wos[128 * 264];
    const int tid = threadIdx.x;
    const int wave = tid >> 6, lane = tid & 63;
    const int quad = lane >> 4, l16 = lane & 15;
    const int row0 = blockIdx.x * 64 + wave * 16;
    f32x4 acc[8];
#pragma unroll
    for (int q = 0; q < 8; ++q) acc[q] = (f32x4){0.f, 0.f, 0.f, 0.f};

    for (int half = 0; half < 2; ++half) {
        __syncthreads();
        for (int e = tid; e < 128 * 32; e += 256) {
            int n = e >> 5, c8 = (e & 31) * 8;
            *(bf16x8*)(wos + n * 264 + c8) = *(const bf16x8*)(wo + n * 512 + half * 256 + c8);
        }
        __syncthreads();
#pragma unroll
        for (int ki = 0; ki < 8; ++ki) {
            bf16x8 a = *(const bf16x8*)(hs + (size_t)(row0 + l16) * 512 + half * 256 + ki * 32 + quad * 8);
#pragma unroll
            for (int tn = 0; tn < 8; ++tn) {
                bf16x8 b = *(const bf16x8*)(wos + (tn * 16 + l16) * 264 + ki * 32 + quad * 8);
                acc[tn] = MFMA16(a, b, acc[tn]);
            }
        }
    }
    float bia[8];
#pragma unroll
    for (int tn = 0; tn < 8; ++tn) bia[tn] = ob[tn * 16 + l16];
#pragma unroll
    for (int reg = 0; reg < 4; ++reg) {
        float v[8];
        float m = -3.4e38f;
#pragma unroll
        for (int tn = 0; tn < 8; ++tn) { v[tn] = acc[tn][reg] + bia[tn]; m = fmaxf(m, v[tn]); }
#pragma unroll
        for (int off = 1; off < 16; off <<= 1) m = fmaxf(m, __shfl_xor(m, off, 64));
        float s = 0.f;
#pragma unroll
        for (int tn = 0; tn < 8; ++tn) s += __expf(v[tn] - m);
#pragma unroll
        for (int off = 1; off < 16; off <<= 1) s += __shfl_xor(s, off, 64);
        float z = m + __logf(s);
        int row = row0 + quad * 4 + reg;
        float* op = out + (size_t)row * 128;
#pragma unroll
        for (int tn = 0; tn < 8; ++tn) op[tn * 16 + l16] = v[tn] - z;
    }
}

extern "C" void kernel_launch(void* const* d_in, const int* in_sizes, int n_in,
                              void* d_out, int out_size, void* d_ws, size_t ws_size,
                              hipStream_t stream) {
    const float* inp     = (const float*)d_in[0];
    const float* img     = (const float*)d_in[1];
    const float* conv1_w = (const float*)d_in[2];
    const float* conv1_b = (const float*)d_in[3];
    const float* conv2_w = (const float*)d_in[4];
    const float* conv2_b = (const float*)d_in[5];
    const float* imgfc_w = (const float*)d_in[6];
    const float* imgfc_b = (const float*)d_in[7];
    const float* xh_w    = (const float*)d_in[8];
    const float* xh_b    = (const float*)d_in[9];
    const float* hh_w    = (const float*)d_in[10];
    const float* hh_b    = (const float*)d_in[11];
    const float* out_w   = (const float*)d_in[12];
    const float* out_b   = (const float*)d_in[13];

    // ws layout (~90 MB). conv1out/feat alias the hs region (dead before
    // lstm_persist writes hs[0]).
    char* ws = (char*)d_ws;
    unsigned short* hs  = (unsigned short*)(ws);                   // [0,64M): [T,B,512] bf16
    float* conv1out     = (float*)(ws);                            // [0,32M) alias
    float* feat         = (float*)(ws + (32u << 20));              // [32,46.2M) alias
    float* e            = (float*)(ws + (64u << 20));              // 2 MB
    float* cbias        = (float*)(ws + (66u << 20));              // 8 KB
    unsigned short* xbf = (unsigned short*)(ws + (67u << 20));     // 16 MB
    unsigned short* wt  = (unsigned short*)(ws + (83u << 20));     // 2.56 MB
    unsigned short* wo  = (unsigned short*)(ws + (86u << 20));     // 128 KB
    unsigned int*  ctr  = (unsigned int*)(ws + (87u << 20));       // 8 x 256B
    float* outp         = (float*)d_out;

    cbias_k<<<8, 256, 0, stream>>>(xh_b, hh_b, cbias, ctr);
    convx_k<<<(T_ * B_ * V_) / 256, 256, 0, stream>>>(inp, xbf);
    convw_k<<<(2048 * 640) / 256, 256, 0, stream>>>(xh_w, hh_w, wt);
    convow_k<<<(128 * 512) / 256, 256, 0, stream>>>(out_w, wo);
    conv1_k<<<(B_ * 8 * 32 * 32) / 256, 256, 0, stream>>>(img, conv1_w, conv1_b, conv1out);
    conv2_k<<<B_, 256, 0, stream>>>(conv1out, conv2_w, conv2_b, feat);
    imgfc_gemm<<<dim3(8, 16), 256, 0, stream>>>(feat, imgfc_w, imgfc_b, e);

    lstm_persist<<<256, 512, 0, stream>>>(xbf, wt, cbias, e, hs, ctr);

    logits_mfma<<<(T_ * B_) / 64, 256, 0, stream>>>(hs, wo, out_b, outp);
}

// Round 8
// 1667.416 us; speedup vs baseline: 1.1623x; 1.1623x over previous
//
#include <hip/hip_runtime.h>

// Model dims
#define T_ 64
#define B_ 1024
#define V_ 128
#define H_ 512

typedef short bf16x8 __attribute__((ext_vector_type(8)));
typedef float f32x4 __attribute__((ext_vector_type(4)));

__device__ __forceinline__ unsigned short f2bf(float f) {
    union { float f; unsigned int i; } v; v.f = f;
    unsigned int x = v.i;
    return (unsigned short)((x + 0x7FFFu + ((x >> 16) & 1u)) >> 16);
}
__device__ __forceinline__ float bf2f(unsigned short u) {
    union { unsigned int i; float f; } v; v.i = ((unsigned int)u) << 16; return v.f;
}
__device__ __forceinline__ float sigm(float x) { return 1.f / (1.f + __expf(-x)); }
__device__ __forceinline__ float tanh_fast(float x) {
    float ax = fabsf(x);
    float t = 1.f - 2.f / (__expf(2.f * ax) + 1.f);   // saturates to 1 on overflow
    return copysignf(t, x);
}
// device-visible store of one bf16, write-through to MALL, no cache flush
__device__ __forceinline__ void store_bf16_wt(unsigned short* p, unsigned short v) {
    unsigned int vv = v;
    asm volatile("global_store_short %0, %1, off sc0 sc1" :: "v"(p), "v"(vv) : "memory");
}

// ---------------- cbias = xh_b + hh_b; zero barrier counters ----------------
__global__ __launch_bounds__(256) void cbias_k(const float* __restrict__ xh_b,
                                               const float* __restrict__ hh_b,
                                               float* __restrict__ cbias,
                                               unsigned int* __restrict__ ctr) {
    int i = blockIdx.x * 256 + threadIdx.x;          // 2048
    cbias[i] = xh_b[i] + hh_b[i];
    if (i < 512) ctr[i] = 0u;                        // 8 counters, 256B apart
}

// ---------------- convert inp fp32 -> bf16 ----------------
__global__ __launch_bounds__(256) void convx_k(const float* __restrict__ x,
                                               unsigned short* __restrict__ xbf) {
    int i = blockIdx.x * 256 + threadIdx.x;          // T*B*V = 8388608
    xbf[i] = f2bf(x[i]);
}

// ---------------- build Wt bf16 [2048][640]: Wt[n][k] = W[k][n] ----------------
__global__ __launch_bounds__(256) void convw_k(const float* __restrict__ xw,
                                               const float* __restrict__ hw,
                                               unsigned short* __restrict__ wt) {
    int i = blockIdx.x * 256 + threadIdx.x;          // 2048*640 = 1310720
    int n = i / 640, k = i - n * 640;
    float v = (k < 128) ? xw[k * 2048 + n] : hw[(k - 128) * 2048 + n];
    wt[i] = f2bf(v);
}

// ---------------- build Wo bf16 [128][512]: Wo[n][k] = out_w[k][n] ----------------
__global__ __launch_bounds__(256) void convow_k(const float* __restrict__ ow,
                                                unsigned short* __restrict__ wo) {
    int i = blockIdx.x * 256 + threadIdx.x;          // 128*512 = 65536
    int n = i >> 9, k = i & 511;
    wo[i] = f2bf(ow[k * 128 + n]);
}

// ---------------- conv1 3x3 pad1 + relu + 2x2 maxpool ----------------
__global__ __launch_bounds__(256) void conv1_k(const float* __restrict__ img,
                                               const float* __restrict__ w,
                                               const float* __restrict__ bias,
                                               float* __restrict__ out) {
    int id = blockIdx.x * 256 + threadIdx.x;         // B*8*32*32 = 8388608
    int px = id & 31, py = (id >> 5) & 31, oc = (id >> 10) & 7, b = id >> 13;
    const float* ip = img + b * 4096;
    float wv[9];
#pragma unroll
    for (int t = 0; t < 9; ++t) wv[t] = w[oc * 9 + t];
    float bs = bias[oc];
    float m = -3.4e38f;
#pragma unroll
    for (int sy = 0; sy < 2; ++sy)
#pragma unroll
    for (int sx = 0; sx < 2; ++sx) {
        int oy = 2 * py + sy, ox = 2 * px + sx;
        float acc = bs;
#pragma unroll
        for (int ky = 0; ky < 3; ++ky) {
            int iy = oy + ky - 1;
            if (iy < 0 || iy > 63) continue;
#pragma unroll
            for (int kx = 0; kx < 3; ++kx) {
                int ix = ox + kx - 1;
                if (ix < 0 || ix > 63) continue;
                acc += ip[iy * 64 + ix] * wv[ky * 3 + kx];
            }
        }
        m = fmaxf(m, acc);
    }
    out[id] = fmaxf(m, 0.f);
}

// ---------------- conv2 5x5 pad1 + relu + 2x2 maxpool ----------------
__device__ __forceinline__ int c2idx(int ic, int y, int x) {
    return ((ic * 34 + y) * 2 + (x & 1)) * 18 + (x >> 1);
}
__global__ __launch_bounds__(256) void conv2_k(const float* __restrict__ in,
                                               const float* __restrict__ w,
                                               const float* __restrict__ bias,
                                               float* __restrict__ feat) {
    __shared__ float in_s[8 * 34 * 36];
    __shared__ float w_s[3200];
    __shared__ float b_s[16];
    int tid = threadIdx.x, b = blockIdx.x;
    for (int e = tid; e < 8 * 34 * 34; e += 256) {
        int ic = e / 1156, r = e - ic * 1156;
        int y = r / 34, xx = r - y * 34;
        float v = 0.f;
        if (y >= 1 && y <= 32 && xx >= 1 && xx <= 32)
            v = in[b * 8192 + ic * 1024 + (y - 1) * 32 + (xx - 1)];
        in_s[c2idx(ic, y, xx)] = v;
    }
    for (int e = tid; e < 3200; e += 256) w_s[e] = w[e];
    if (tid < 16) b_s[tid] = bias[tid];
    __syncthreads();
    for (int o = tid; o < 3600; o += 256) {
        int oc = o / 225, p = o - oc * 225;
        int py = p / 15, px = p - py * 15;
        float a00, a01, a10, a11;
        a00 = a01 = a10 = a11 = b_s[oc];
        for (int ic = 0; ic < 8; ++ic) {
            const float* wp = w_s + (oc * 8 + ic) * 25;
#pragma unroll
            for (int ky = 0; ky < 5; ++ky) {
                int y0 = 2 * py + ky;
                float r0[6], r1[6];
#pragma unroll
                for (int xx = 0; xx < 6; ++xx) {
                    r0[xx] = in_s[c2idx(ic, y0,     2 * px + xx)];
                    r1[xx] = in_s[c2idx(ic, y0 + 1, 2 * px + xx)];
                }
#pragma unroll
                for (int kx = 0; kx < 5; ++kx) {
                    float wv = wp[ky * 5 + kx];
                    a00 += r0[kx    ] * wv;
                    a01 += r0[kx + 1] * wv;
                    a10 += r1[kx    ] * wv;
                    a11 += r1[kx + 1] * wv;
                }
            }
        }
        float mx = fmaxf(fmaxf(a00, a01), fmaxf(a10, a11));
        feat[b * 3600 + o] = fmaxf(mx, 0.f);
    }
}

// ---------------- imgfc: e = relu(feat @ W + b), M=1024 N=512 K=3600 ----------------
__global__ __launch_bounds__(256) void imgfc_gemm(const float* __restrict__ A,
                                                  const float* __restrict__ W,
                                                  const float* __restrict__ bias,
                                                  float* __restrict__ E) {
    __shared__ __align__(16) float As[16][68];
    __shared__ __align__(16) float Bs[16][68];
    const int tid = threadIdx.x;
    const int tx = tid & 15, ty = tid >> 4;
    const int row0 = blockIdx.y * 64, col0 = blockIdx.x * 64;
    const int am = tid >> 2, ak = (tid & 3) * 4;
    const int bk = tid >> 4, bn = (tid & 15) * 4;
    float acc[4][4] = {};
    for (int k0 = 0; k0 < 3600; k0 += 16) {
        float4 fa = *(const float4*)(A + (row0 + am) * 3600 + k0 + ak);
        float4 fb = *(const float4*)(W + (k0 + bk) * 512 + col0 + bn);
        __syncthreads();
        As[ak + 0][am] = fa.x; As[ak + 1][am] = fa.y; As[ak + 2][am] = fa.z; As[ak + 3][am] = fa.w;
        Bs[bk][bn + 0] = fb.x; Bs[bk][bn + 1] = fb.y; Bs[bk][bn + 2] = fb.z; Bs[bk][bn + 3] = fb.w;
        __syncthreads();
#pragma unroll
        for (int kk = 0; kk < 16; ++kk) {
            float4 av = *(const float4*)(&As[kk][ty * 4]);
            float4 bv = *(const float4*)(&Bs[kk][tx * 4]);
            float a[4] = {av.x, av.y, av.z, av.w};
            float bb[4] = {bv.x, bv.y, bv.z, bv.w};
#pragma unroll
            for (int i = 0; i < 4; ++i)
#pragma unroll
            for (int j = 0; j < 4; ++j) acc[i][j] += a[i] * bb[j];
        }
    }
#pragma unroll
    for (int i = 0; i < 4; ++i) {
        int r = row0 + ty * 4 + i;
#pragma unroll
        for (int j = 0; j < 4; ++j) {
            int cI = col0 + tx * 4 + j;
            E[r * 512 + cI] = fmaxf(acc[i][j] + bias[cI], 0.f);
        }
    }
}

#define MFMA16(a, b, c) __builtin_amdgcn_mfma_f32_16x16x32_bf16((a), (b), (c), 0, 0, 0)

// ---------------- persistent LSTM: all 64 steps in one dispatch ----------------
// 256 blocks x 512 threads. Block = (rg, jblk) with rg = blockIdx&7 so all 32
// blocks of an rg share one XCD (i%8 dispatch heuristic; locality only, sc1
// write-through keeps correctness if the mapping differs). Wave = (rt2, gp):
// 2x16 rows, 2 gates, B-slice register-resident. Per-step cross-block sync:
// one relaxed agent fetch_add per block (after __syncthreads drains sc1
// stores), thread-0-only poll, __syncthreads release. Counters 256B apart.
__global__ __launch_bounds__(512, 2) void lstm_persist(
        const unsigned short* __restrict__ xbf,   // [T,B,128] bf16
        const unsigned short* __restrict__ wt,    // [2048,640] bf16
        const float* __restrict__ cbias,          // [2048]
        const float* __restrict__ eimg,           // [B,512]
        unsigned short* __restrict__ hs,          // [T,B,512] bf16
        unsigned int* __restrict__ ctr) {         // [8*64], 256B stride
    __shared__ float ex_s[128 * 16 * 2];          // (g,o) exchange, 16 KB
    const int tid = threadIdx.x;
    const int wave = tid >> 6, lane = tid & 63;
    const int quad = lane >> 4, l16 = lane & 15;
    const int rt2 = wave & 3, gp = wave >> 2;
    const int rg = blockIdx.x & 7;                // XCD swizzle
    const int jblk = blockIdx.x >> 3;
    const int j0 = jblk * 16;
    const int rowbase = rg * 128 + rt2 * 32;      // two 16-row tiles: +0, +16
    unsigned int* myctr = ctr + rg * 64;

    // B-fragments for this wave's two gates, all 20 k-chunks (k=0..639)
    bf16x8 bg[2][20];
#pragma unroll
    for (int gg = 0; gg < 2; ++gg) {
        const unsigned short* wrow = wt + (size_t)((gp * 2 + gg) * 512 + j0 + l16) * 640;
#pragma unroll
        for (int kk = 0; kk < 20; ++kk)
            bg[gg][kk] = *(const bf16x8*)(wrow + kk * 32 + quad * 8);
    }
    const int j = j0 + l16;
    float cb[4] = {cbias[j], cbias[512 + j], cbias[1024 + j], cbias[1536 + j]};

    float cst[2][4];
    f32x4 acc[2][2];
#pragma unroll
    for (int tt = 0; tt < 2; ++tt)
#pragma unroll
        for (int gg = 0; gg < 2; ++gg) acc[tt][gg] = (f32x4){0.f, 0.f, 0.f, 0.f};

    // x-part for t=0
#pragma unroll
    for (int kk = 0; kk < 4; ++kk) {
        bf16x8 a0 = *(const bf16x8*)(xbf + (size_t)(rowbase + l16) * 128 + kk * 32 + quad * 8);
        bf16x8 a1 = *(const bf16x8*)(xbf + (size_t)(rowbase + 16 + l16) * 128 + kk * 32 + quad * 8);
        acc[0][0] = MFMA16(a0, bg[0][kk], acc[0][0]);
        acc[0][1] = MFMA16(a0, bg[1][kk], acc[0][1]);
        acc[1][0] = MFMA16(a1, bg[0][kk], acc[1][0]);
        acc[1][1] = MFMA16(a1, bg[1][kk], acc[1][1]);
    }

#pragma unroll 1
    for (int t = 0; t < T_; ++t) {
        if (t > 0) {
            __syncthreads();                      // A: drains prior-step sc1 stores (vmcnt)
            if (tid == 0) {
                __hip_atomic_fetch_add(myctr, 1u, __ATOMIC_RELAXED, __HIP_MEMORY_SCOPE_AGENT);
                unsigned int target = 32u * (unsigned int)t;
                int guard = 0;
                while (__hip_atomic_load(myctr, __ATOMIC_RELAXED, __HIP_MEMORY_SCOPE_AGENT) < target
                       && ++guard < (1 << 27))
                    __builtin_amdgcn_s_sleep(4);
            }
            __syncthreads();                      // B: release
            const unsigned short* hp = hs + (size_t)(t - 1) * (B_ * H_);
#pragma unroll
            for (int kk = 0; kk < 16; ++kk) {
                bf16x8 a0 = *(const bf16x8*)(hp + (size_t)(rowbase + l16) * 512 + kk * 32 + quad * 8);
                bf16x8 a1 = *(const bf16x8*)(hp + (size_t)(rowbase + 16 + l16) * 512 + kk * 32 + quad * 8);
                acc[0][0] = MFMA16(a0, bg[0][4 + kk], acc[0][0]);
                acc[0][1] = MFMA16(a0, bg[1][4 + kk], acc[0][1]);
                acc[1][0] = MFMA16(a1, bg[0][4 + kk], acc[1][0]);
                acc[1][1] = MFMA16(a1, bg[1][4 + kk], acc[1][1]);
            }
        }
        if (gp == 1) {
#pragma unroll
            for (int tt = 0; tt < 2; ++tt)
#pragma unroll
                for (int reg = 0; reg < 4; ++reg) {
                    int rl = rt2 * 32 + tt * 16 + quad * 4 + reg;
                    ex_s[(rl * 16 + l16) * 2 + 0] = acc[tt][0][reg];
                    ex_s[(rl * 16 + l16) * 2 + 1] = acc[tt][1][reg];
                }
        }
        __syncthreads();                          // C: exchange visible
        if (gp == 0) {
            unsigned short* ho = hs + (size_t)t * (B_ * H_);
#pragma unroll
            for (int tt = 0; tt < 2; ++tt)
#pragma unroll
                for (int reg = 0; reg < 4; ++reg) {
                    int rl = rt2 * 32 + tt * 16 + quad * 4 + reg;
                    int row = rg * 128 + rl;
                    size_t o = (size_t)row * 512 + j;
                    float ea = (t == 0) ? eimg[o] : 0.f;
                    float iv = sigm(acc[tt][0][reg] + cb[0] + ea);
                    float fv = sigm(acc[tt][1][reg] + cb[1] + ea);
                    float gv = tanh_fast(ex_s[(rl * 16 + l16) * 2 + 0] + cb[2] + ea);
                    float ov = sigm(ex_s[(rl * 16 + l16) * 2 + 1] + cb[3] + ea);
                    float co = (t == 0) ? 0.f : cst[tt][reg];
                    float cn = fv * co + iv * gv;
                    cst[tt][reg] = cn;
                    store_bf16_wt(ho + o, f2bf(ov * tanh_fast(cn)));
                }
        }
        if (t < T_ - 1) {
            // pre-compute x-part(t+1) while the stores drain / barrier converges
#pragma unroll
            for (int tt = 0; tt < 2; ++tt)
#pragma unroll
                for (int gg = 0; gg < 2; ++gg) acc[tt][gg] = (f32x4){0.f, 0.f, 0.f, 0.f};
            const unsigned short* xtp = xbf + (size_t)(t + 1) * (B_ * V_);
#pragma unroll
            for (int kk = 0; kk < 4; ++kk) {
                bf16x8 a0 = *(const bf16x8*)(xtp + (size_t)(rowbase + l16) * 128 + kk * 32 + quad * 8);
                bf16x8 a1 = *(const bf16x8*)(xtp + (size_t)(rowbase + 16 + l16) * 128 + kk * 32 + quad * 8);
                acc[0][0] = MFMA16(a0, bg[0][kk], acc[0][0]);
                acc[0][1] = MFMA16(a0, bg[1][kk], acc[0][1]);
                acc[1][0] = MFMA16(a1, bg[0][kk], acc[1][0]);
                acc[1][1] = MFMA16(a1, bg[1][kk], acc[1][1]);
            }
        }
    }
}

// ---------------- logits + log_softmax via MFMA ----------------
__global__ __launch_bounds__(256, 2) void logits_mfma(
        const unsigned short* __restrict__ hs,    // [65536,512] bf16
        const unsigned short* __restrict__ wo,    // [128][512] bf16, k-major
        const float* __restrict__ ob,             // [128]
        float* __restrict__ out) {                // [65536,128]
    __shared__ unsigned short wos[128 * 264];
    const int tid = threadIdx.x;
    const int wave = tid >> 6, lane = tid & 63;
    const int quad = lane >> 4, l16 = lane & 15;
    const int row0 = blockIdx.x * 64 + wave * 16;
    f32x4 acc[8];
#pragma unroll
    for (int q = 0; q < 8; ++q) acc[q] = (f32x4){0.f, 0.f, 0.f, 0.f};

    for (int half = 0; half < 2; ++half) {
        __syncthreads();
        for (int e = tid; e < 128 * 32; e += 256) {
            int n = e >> 5, c8 = (e & 31) * 8;
            *(bf16x8*)(wos + n * 264 + c8) = *(const bf16x8*)(wo + n * 512 + half * 256 + c8);
        }
        __syncthreads();
#pragma unroll
        for (int ki = 0; ki < 8; ++ki) {
            bf16x8 a = *(const bf16x8*)(hs + (size_t)(row0 + l16) * 512 + half * 256 + ki * 32 + quad * 8);
#pragma unroll
            for (int tn = 0; tn < 8; ++tn) {
                bf16x8 b = *(const bf16x8*)(wos + (tn * 16 + l16) * 264 + ki * 32 + quad * 8);
                acc[tn] = MFMA16(a, b, acc[tn]);
            }
        }
    }
    float bia[8];
#pragma unroll
    for (int tn = 0; tn < 8; ++tn) bia[tn] = ob[tn * 16 + l16];
#pragma unroll
    for (int reg = 0; reg < 4; ++reg) {
        float v[8];
        float m = -3.4e38f;
#pragma unroll
        for (int tn = 0; tn < 8; ++tn) { v[tn] = acc[tn][reg] + bia[tn]; m = fmaxf(m, v[tn]); }
#pragma unroll
        for (int off = 1; off < 16; off <<= 1) m = fmaxf(m, __shfl_xor(m, off, 64));
        float s = 0.f;
#pragma unroll
        for (int tn = 0; tn < 8; ++tn) s += __expf(v[tn] - m);
#pragma unroll
        for (int off = 1; off < 16; off <<= 1) s += __shfl_xor(s, off, 64);
        float z = m + __logf(s);
        int row = row0 + quad * 4 + reg;
        float* op = out + (size_t)row * 128;
#pragma unroll
        for (int tn = 0; tn < 8; ++tn) op[tn * 16 + l16] = v[tn] - z;
    }
}

extern "C" void kernel_launch(void* const* d_in, const int* in_sizes, int n_in,
                              void* d_out, int out_size, void* d_ws, size_t ws_size,
                              hipStream_t stream) {
    const float* inp     = (const float*)d_in[0];
    const float* img     = (const float*)d_in[1];
    const float* conv1_w = (const float*)d_in[2];
    const float* conv1_b = (const float*)d_in[3];
    const float* conv2_w = (const float*)d_in[4];
    const float* conv2_b = (const float*)d_in[5];
    const float* imgfc_w = (const float*)d_in[6];
    const float* imgfc_b = (const float*)d_in[7];
    const float* xh_w    = (const float*)d_in[8];
    const float* xh_b    = (const float*)d_in[9];
    const float* hh_w    = (const float*)d_in[10];
    const float* hh_b    = (const float*)d_in[11];
    const float* out_w   = (const float*)d_in[12];
    const float* out_b   = (const float*)d_in[13];

    // ws layout (~90 MB). conv1out/feat alias the hs region (dead before
    // lstm_persist writes hs[0]; dispatch-boundary acquire/release keeps
    // the aliasing coherent across kernels).
    char* ws = (char*)d_ws;
    unsigned short* hs  = (unsigned short*)(ws);                   // [0,64M): [T,B,512] bf16
    float* conv1out     = (float*)(ws);                            // [0,32M) alias
    float* feat         = (float*)(ws + (32u << 20));              // [32,46.2M) alias
    float* e            = (float*)(ws + (64u << 20));              // 2 MB
    float* cbias        = (float*)(ws + (66u << 20));              // 8 KB
    unsigned short* xbf = (unsigned short*)(ws + (67u << 20));     // 16 MB
    unsigned short* wt  = (unsigned short*)(ws + (83u << 20));     // 2.56 MB
    unsigned short* wo  = (unsigned short*)(ws + (86u << 20));     // 128 KB
    unsigned int*  ctr  = (unsigned int*)(ws + (87u << 20));       // 8 x 256B
    float* outp         = (float*)d_out;

    cbias_k<<<8, 256, 0, stream>>>(xh_b, hh_b, cbias, ctr);
    convx_k<<<(T_ * B_ * V_) / 256, 256, 0, stream>>>(inp, xbf);
    convw_k<<<(2048 * 640) / 256, 256, 0, stream>>>(xh_w, hh_w, wt);
    convow_k<<<(128 * 512) / 256, 256, 0, stream>>>(out_w, wo);
    conv1_k<<<(B_ * 8 * 32 * 32) / 256, 256, 0, stream>>>(img, conv1_w, conv1_b, conv1out);
    conv2_k<<<B_, 256, 0, stream>>>(conv1out, conv2_w, conv2_b, feat);
    imgfc_gemm<<<dim3(8, 16), 256, 0, stream>>>(feat, imgfc_w, imgfc_b, e);

    lstm_persist<<<256, 512, 0, stream>>>(xbf, wt, cbias, e, hs, ctr);

    logits_mfma<<<(T_ * B_) / 64, 256, 0, stream>>>(hs, wo, out_b, outp);
}

// Round 9
// 1216.607 us; speedup vs baseline: 1.5929x; 1.3705x over previous
//
#include <hip/hip_runtime.h>

// Model dims
#define T_ 64
#define B_ 1024
#define V_ 128
#define H_ 512

typedef short bf16x8 __attribute__((ext_vector_type(8)));
typedef float f32x4 __attribute__((ext_vector_type(4)));

__device__ __forceinline__ unsigned short f2bf(float f) {
    union { float f; unsigned int i; } v; v.f = f;
    unsigned int x = v.i;
    return (unsigned short)((x + 0x7FFFu + ((x >> 16) & 1u)) >> 16);
}
__device__ __forceinline__ float bf2f(unsigned short u) {
    union { unsigned int i; float f; } v; v.i = ((unsigned int)u) << 16; return v.f;
}
__device__ __forceinline__ float sigm(float x) { return 1.f / (1.f + __expf(-x)); }
__device__ __forceinline__ float tanh_fast(float x) {
    float ax = fabsf(x);
    float t = 1.f - 2.f / (__expf(2.f * ax) + 1.f);   // saturates to 1 on overflow
    return copysignf(t, x);
}
// device-visible store of one bf16, write-through to MALL, no cache flush
__device__ __forceinline__ void store_bf16_wt(unsigned short* p, unsigned short v) {
    unsigned int vv = v;
    asm volatile("global_store_short %0, %1, off sc0 sc1" :: "v"(p), "v"(vv) : "memory");
}

// ---------------- cbias = xh_b + hh_b; zero barrier counters ----------------
__global__ __launch_bounds__(256) void cbias_k(const float* __restrict__ xh_b,
                                               const float* __restrict__ hh_b,
                                               float* __restrict__ cbias,
                                               unsigned int* __restrict__ ctr) {
    int i = blockIdx.x * 256 + threadIdx.x;          // 2048
    cbias[i] = xh_b[i] + hh_b[i];
    if (i < 512) ctr[i] = 0u;                        // 8 counters, 256B apart
}

// ---------------- convert inp fp32 -> bf16 ----------------
__global__ __launch_bounds__(256) void convx_k(const float* __restrict__ x,
                                               unsigned short* __restrict__ xbf) {
    int i = blockIdx.x * 256 + threadIdx.x;          // T*B*V = 8388608
    xbf[i] = f2bf(x[i]);
}

// ---------------- build Wt bf16 [2048][640]: Wt[n][k] = W[k][n] ----------------
__global__ __launch_bounds__(256) void convw_k(const float* __restrict__ xw,
                                               const float* __restrict__ hw,
                                               unsigned short* __restrict__ wt) {
    int i = blockIdx.x * 256 + threadIdx.x;          // 2048*640 = 1310720
    int n = i / 640, k = i - n * 640;
    float v = (k < 128) ? xw[k * 2048 + n] : hw[(k - 128) * 2048 + n];
    wt[i] = f2bf(v);
}

// ---------------- build Wo bf16 [128][512]: Wo[n][k] = out_w[k][n] ----------------
__global__ __launch_bounds__(256) void convow_k(const float* __restrict__ ow,
                                                unsigned short* __restrict__ wo) {
    int i = blockIdx.x * 256 + threadIdx.x;          // 128*512 = 65536
    int n = i >> 9, k = i & 511;
    wo[i] = f2bf(ow[k * 128 + n]);
}

// ---------------- conv1 3x3 pad1 + relu + 2x2 maxpool ----------------
__global__ __launch_bounds__(256) void conv1_k(const float* __restrict__ img,
                                               const float* __restrict__ w,
                                               const float* __restrict__ bias,
                                               float* __restrict__ out) {
    int id = blockIdx.x * 256 + threadIdx.x;         // B*8*32*32 = 8388608
    int px = id & 31, py = (id >> 5) & 31, oc = (id >> 10) & 7, b = id >> 13;
    const float* ip = img + b * 4096;
    float wv[9];
#pragma unroll
    for (int t = 0; t < 9; ++t) wv[t] = w[oc * 9 + t];
    float bs = bias[oc];
    float m = -3.4e38f;
#pragma unroll
    for (int sy = 0; sy < 2; ++sy)
#pragma unroll
    for (int sx = 0; sx < 2; ++sx) {
        int oy = 2 * py + sy, ox = 2 * px + sx;
        float acc = bs;
#pragma unroll
        for (int ky = 0; ky < 3; ++ky) {
            int iy = oy + ky - 1;
            if (iy < 0 || iy > 63) continue;
#pragma unroll
            for (int kx = 0; kx < 3; ++kx) {
                int ix = ox + kx - 1;
                if (ix < 0 || ix > 63) continue;
                acc += ip[iy * 64 + ix] * wv[ky * 3 + kx];
            }
        }
        m = fmaxf(m, acc);
    }
    out[id] = fmaxf(m, 0.f);
}

// ---------------- conv2 5x5 pad1 + relu + 2x2 maxpool ----------------
__device__ __forceinline__ int c2idx(int ic, int y, int x) {
    return ((ic * 34 + y) * 2 + (x & 1)) * 18 + (x >> 1);
}
__global__ __launch_bounds__(256) void conv2_k(const float* __restrict__ in,
                                               const float* __restrict__ w,
                                               const float* __restrict__ bias,
                                               float* __restrict__ feat) {
    __shared__ float in_s[8 * 34 * 36];
    __shared__ float w_s[3200];
    __shared__ float b_s[16];
    int tid = threadIdx.x, b = blockIdx.x;
    for (int e = tid; e < 8 * 34 * 34; e += 256) {
        int ic = e / 1156, r = e - ic * 1156;
        int y = r / 34, xx = r - y * 34;
        float v = 0.f;
        if (y >= 1 && y <= 32 && xx >= 1 && xx <= 32)
            v = in[b * 8192 + ic * 1024 + (y - 1) * 32 + (xx - 1)];
        in_s[c2idx(ic, y, xx)] = v;
    }
    for (int e = tid; e < 3200; e += 256) w_s[e] = w[e];
    if (tid < 16) b_s[tid] = bias[tid];
    __syncthreads();
    for (int o = tid; o < 3600; o += 256) {
        int oc = o / 225, p = o - oc * 225;
        int py = p / 15, px = p - py * 15;
        float a00, a01, a10, a11;
        a00 = a01 = a10 = a11 = b_s[oc];
        for (int ic = 0; ic < 8; ++ic) {
            const float* wp = w_s + (oc * 8 + ic) * 25;
#pragma unroll
            for (int ky = 0; ky < 5; ++ky) {
                int y0 = 2 * py + ky;
                float r0[6], r1[6];
#pragma unroll
                for (int xx = 0; xx < 6; ++xx) {
                    r0[xx] = in_s[c2idx(ic, y0,     2 * px + xx)];
                    r1[xx] = in_s[c2idx(ic, y0 + 1, 2 * px + xx)];
                }
#pragma unroll
                for (int kx = 0; kx < 5; ++kx) {
                    float wv = wp[ky * 5 + kx];
                    a00 += r0[kx    ] * wv;
                    a01 += r0[kx + 1] * wv;
                    a10 += r1[kx    ] * wv;
                    a11 += r1[kx + 1] * wv;
                }
            }
        }
        float mx = fmaxf(fmaxf(a00, a01), fmaxf(a10, a11));
        feat[b * 3600 + o] = fmaxf(mx, 0.f);
    }
}

// ---------------- imgfc: e = relu(feat @ W + b), M=1024 N=512 K=3600 ----------------
__global__ __launch_bounds__(256) void imgfc_gemm(const float* __restrict__ A,
                                                  const float* __restrict__ W,
                                                  const float* __restrict__ bias,
                                                  float* __restrict__ E) {
    __shared__ __align__(16) float As[16][68];
    __shared__ __align__(16) float Bs[16][68];
    const int tid = threadIdx.x;
    const int tx = tid & 15, ty = tid >> 4;
    const int row0 = blockIdx.y * 64, col0 = blockIdx.x * 64;
    const int am = tid >> 2, ak = (tid & 3) * 4;
    const int bk = tid >> 4, bn = (tid & 15) * 4;
    float acc[4][4] = {};
    for (int k0 = 0; k0 < 3600; k0 += 16) {
        float4 fa = *(const float4*)(A + (row0 + am) * 3600 + k0 + ak);
        float4 fb = *(const float4*)(W + (k0 + bk) * 512 + col0 + bn);
        __syncthreads();
        As[ak + 0][am] = fa.x; As[ak + 1][am] = fa.y; As[ak + 2][am] = fa.z; As[ak + 3][am] = fa.w;
        Bs[bk][bn + 0] = fb.x; Bs[bk][bn + 1] = fb.y; Bs[bk][bn + 2] = fb.z; Bs[bk][bn + 3] = fb.w;
        __syncthreads();
#pragma unroll
        for (int kk = 0; kk < 16; ++kk) {
            float4 av = *(const float4*)(&As[kk][ty * 4]);
            float4 bv = *(const float4*)(&Bs[kk][tx * 4]);
            float a[4] = {av.x, av.y, av.z, av.w};
            float bb[4] = {bv.x, bv.y, bv.z, bv.w};
#pragma unroll
            for (int i = 0; i < 4; ++i)
#pragma unroll
            for (int j = 0; j < 4; ++j) acc[i][j] += a[i] * bb[j];
        }
    }
#pragma unroll
    for (int i = 0; i < 4; ++i) {
        int r = row0 + ty * 4 + i;
#pragma unroll
        for (int j = 0; j < 4; ++j) {
            int cI = col0 + tx * 4 + j;
            E[r * 512 + cI] = fmaxf(acc[i][j] + bias[cI], 0.f);
        }
    }
}

#define MFMA16(a, b, c) __builtin_amdgcn_mfma_f32_16x16x32_bf16((a), (b), (c), 0, 0, 0)

// ---------------- persistent LSTM: all 64 steps in one dispatch ----------------
// 256 blocks x 512 threads (8 waves). Block = (rg, jblk), rg = blockIdx&7 (XCD
// swizzle, locality only). Wave = 16 rows x 16 cols x ALL 4 gates; B-slice for
// the block (64 wt-rows x 640 k = 81 KB) lives in LDS — staged once, read via
// conflict-free padded ds_read_b128 every step (structural residency; the
// register-array version was silently demoted to per-step L2 re-loads, R8).
// Cross-block sync: sc0/sc1 write-through hs stores; one relaxed agent
// fetch_add per block per step + tid0-only poll; counters 256B apart.
__global__ __launch_bounds__(512, 2) void lstm_persist(
        const unsigned short* __restrict__ xbf,   // [T,B,128] bf16
        const unsigned short* __restrict__ wt,    // [2048,640] bf16
        const float* __restrict__ cbias,          // [2048]
        const float* __restrict__ eimg,           // [B,512]
        unsigned short* __restrict__ hs,          // [T,B,512] bf16
        unsigned int* __restrict__ ctr) {         // [8*64], 256B stride
    extern __shared__ unsigned short w_s[];       // [64][648] padded (81 KB)
    const int tid = threadIdx.x;
    const int wave = tid >> 6, lane = tid & 63;
    const int quad = lane >> 4, l16 = lane & 15;
    const int rg = blockIdx.x & 7;                // XCD swizzle
    const int jblk = blockIdx.x >> 3;
    const int j0 = jblk * 16;
    const int rowbase = rg * 128 + wave * 16;
    unsigned int* myctr = ctr + rg * 64;

    // stage the block's weight slice: 64 rows (4 gates x 16 j) x 640 k
    for (int e = tid; e < 64 * 80; e += 512) {
        int r = e / 80, c8 = (e - r * 80) * 8;
        int g = r >> 4, rr = r & 15;
        *(bf16x8*)(w_s + r * 648 + c8) =
            *(const bf16x8*)(wt + (size_t)(g * 512 + j0 + rr) * 640 + c8);
    }
    const int j = j0 + l16;
    const float cb0 = cbias[j], cb1 = cbias[512 + j], cb2 = cbias[1024 + j], cb3 = cbias[1536 + j];
    __syncthreads();

    float cst[4];
    f32x4 acc[4];
#pragma unroll
    for (int g = 0; g < 4; ++g) acc[g] = (f32x4){0.f, 0.f, 0.f, 0.f};

    // x-part for t=0
#pragma unroll
    for (int kk = 0; kk < 4; ++kk) {
        bf16x8 a = *(const bf16x8*)(xbf + (size_t)(rowbase + l16) * 128 + kk * 32 + quad * 8);
#pragma unroll
        for (int g = 0; g < 4; ++g) {
            bf16x8 b = *(const bf16x8*)(w_s + (size_t)(g * 16 + l16) * 648 + kk * 32 + quad * 8);
            acc[g] = MFMA16(a, b, acc[g]);
        }
    }

#pragma unroll 1
    for (int t = 0; t < T_; ++t) {
        if (t > 0) {
            __syncthreads();                      // A: drains prior-step sc1 stores (vmcnt)
            if (tid == 0) {
                __hip_atomic_fetch_add(myctr, 1u, __ATOMIC_RELAXED, __HIP_MEMORY_SCOPE_AGENT);
                unsigned int target = 32u * (unsigned int)t;
                int guard = 0;
                while (__hip_atomic_load(myctr, __ATOMIC_RELAXED, __HIP_MEMORY_SCOPE_AGENT) < target
                       && ++guard < (1 << 27))
                    __builtin_amdgcn_s_sleep(1);
            }
            __syncthreads();                      // B: release
            const unsigned short* hp = hs + (size_t)(t - 1) * (B_ * H_);
#pragma unroll
            for (int kk = 0; kk < 16; ++kk) {
                bf16x8 a = *(const bf16x8*)(hp + (size_t)(rowbase + l16) * 512 + kk * 32 + quad * 8);
#pragma unroll
                for (int g = 0; g < 4; ++g) {
                    bf16x8 b = *(const bf16x8*)(w_s + (size_t)(g * 16 + l16) * 648 + 128 + kk * 32 + quad * 8);
                    acc[g] = MFMA16(a, b, acc[g]);
                }
            }
        }
        // epilogue: C/D layout col=l16, row=quad*4+reg
        unsigned short* ho = hs + (size_t)t * (B_ * H_);
#pragma unroll
        for (int reg = 0; reg < 4; ++reg) {
            int row = rowbase + quad * 4 + reg;
            size_t o = (size_t)row * 512 + j;
            float ea = (t == 0) ? eimg[o] : 0.f;
            float iv = sigm(acc[0][reg] + cb0 + ea);
            float fv = sigm(acc[1][reg] + cb1 + ea);
            float gv = tanh_fast(acc[2][reg] + cb2 + ea);
            float ov = sigm(acc[3][reg] + cb3 + ea);
            float co = (t == 0) ? 0.f : cst[reg];
            float cn = fv * co + iv * gv;
            cst[reg] = cn;
            store_bf16_wt(ho + o, f2bf(ov * tanh_fast(cn)));
        }
        if (t < T_ - 1) {
            // pre-compute x-part(t+1) while the stores drain / barrier converges
#pragma unroll
            for (int g = 0; g < 4; ++g) acc[g] = (f32x4){0.f, 0.f, 0.f, 0.f};
            const unsigned short* xtp = xbf + (size_t)(t + 1) * (B_ * V_);
#pragma unroll
            for (int kk = 0; kk < 4; ++kk) {
                bf16x8 a = *(const bf16x8*)(xtp + (size_t)(rowbase + l16) * 128 + kk * 32 + quad * 8);
#pragma unroll
                for (int g = 0; g < 4; ++g) {
                    bf16x8 b = *(const bf16x8*)(w_s + (size_t)(g * 16 + l16) * 648 + kk * 32 + quad * 8);
                    acc[g] = MFMA16(a, b, acc[g]);
                }
            }
        }
    }
}

// ---------------- logits + log_softmax via MFMA ----------------
__global__ __launch_bounds__(256, 2) void logits_mfma(
        const unsigned short* __restrict__ hs,    // [65536,512] bf16
        const unsigned short* __restrict__ wo,    // [128][512] bf16, k-major
        const float* __restrict__ ob,             // [128]
        float* __restrict__ out) {                // [65536,128]
    __shared__ unsigned short wos[128 * 264];
    const int tid = threadIdx.x;
    const int wave = tid >> 6, lane = tid & 63;
    const int quad = lane >> 4, l16 = lane & 15;
    const int row0 = blockIdx.x * 64 + wave * 16;
    f32x4 acc[8];
#pragma unroll
    for (int q = 0; q < 8; ++q) acc[q] = (f32x4){0.f, 0.f, 0.f, 0.f};

    for (int half = 0; half < 2; ++half) {
        __syncthreads();
        for (int e = tid; e < 128 * 32; e += 256) {
            int n = e >> 5, c8 = (e & 31) * 8;
            *(bf16x8*)(wos + n * 264 + c8) = *(const bf16x8*)(wo + n * 512 + half * 256 + c8);
        }
        __syncthreads();
#pragma unroll
        for (int ki = 0; ki < 8; ++ki) {
            bf16x8 a = *(const bf16x8*)(hs + (size_t)(row0 + l16) * 512 + half * 256 + ki * 32 + quad * 8);
#pragma unroll
            for (int tn = 0; tn < 8; ++tn) {
                bf16x8 b = *(const bf16x8*)(wos + (tn * 16 + l16) * 264 + ki * 32 + quad * 8);
                acc[tn] = MFMA16(a, b, acc[tn]);
            }
        }
    }
    float bia[8];
#pragma unroll
    for (int tn = 0; tn < 8; ++tn) bia[tn] = ob[tn * 16 + l16];
#pragma unroll
    for (int reg = 0; reg < 4; ++reg) {
        float v[8];
        float m = -3.4e38f;
#pragma unroll
        for (int tn = 0; tn < 8; ++tn) { v[tn] = acc[tn][reg] + bia[tn]; m = fmaxf(m, v[tn]); }
#pragma unroll
        for (int off = 1; off < 16; off <<= 1) m = fmaxf(m, __shfl_xor(m, off, 64));
        float s = 0.f;
#pragma unroll
        for (int tn = 0; tn < 8; ++tn) s += __expf(v[tn] - m);
#pragma unroll
        for (int off = 1; off < 16; off <<= 1) s += __shfl_xor(s, off, 64);
        float z = m + __logf(s);
        int row = row0 + quad * 4 + reg;
        float* op = out + (size_t)row * 128;
#pragma unroll
        for (int tn = 0; tn < 8; ++tn) op[tn * 16 + l16] = v[tn] - z;
    }
}

extern "C" void kernel_launch(void* const* d_in, const int* in_sizes, int n_in,
                              void* d_out, int out_size, void* d_ws, size_t ws_size,
                              hipStream_t stream) {
    const float* inp     = (const float*)d_in[0];
    const float* img     = (const float*)d_in[1];
    const float* conv1_w = (const float*)d_in[2];
    const float* conv1_b = (const float*)d_in[3];
    const float* conv2_w = (const float*)d_in[4];
    const float* conv2_b = (const float*)d_in[5];
    const float* imgfc_w = (const float*)d_in[6];
    const float* imgfc_b = (const float*)d_in[7];
    const float* xh_w    = (const float*)d_in[8];
    const float* xh_b    = (const float*)d_in[9];
    const float* hh_w    = (const float*)d_in[10];
    const float* hh_b    = (const float*)d_in[11];
    const float* out_w   = (const float*)d_in[12];
    const float* out_b   = (const float*)d_in[13];

    // ws layout (~90 MB). conv1out/feat alias the hs region (dead before
    // lstm_persist writes hs[0]).
    char* ws = (char*)d_ws;
    unsigned short* hs  = (unsigned short*)(ws);                   // [0,64M): [T,B,512] bf16
    float* conv1out     = (float*)(ws);                            // [0,32M) alias
    float* feat         = (float*)(ws + (32u << 20));              // [32,46.2M) alias
    float* e            = (float*)(ws + (64u << 20));              // 2 MB
    float* cbias        = (float*)(ws + (66u << 20));              // 8 KB
    unsigned short* xbf = (unsigned short*)(ws + (67u << 20));     // 16 MB
    unsigned short* wt  = (unsigned short*)(ws + (83u << 20));     // 2.56 MB
    unsigned short* wo  = (unsigned short*)(ws + (86u << 20));     // 128 KB
    unsigned int*  ctr  = (unsigned int*)(ws + (87u << 20));       // 8 x 256B
    float* outp         = (float*)d_out;

    cbias_k<<<8, 256, 0, stream>>>(xh_b, hh_b, cbias, ctr);
    convx_k<<<(T_ * B_ * V_) / 256, 256, 0, stream>>>(inp, xbf);
    convw_k<<<(2048 * 640) / 256, 256, 0, stream>>>(xh_w, hh_w, wt);
    convow_k<<<(128 * 512) / 256, 256, 0, stream>>>(out_w, wo);
    conv1_k<<<(B_ * 8 * 32 * 32) / 256, 256, 0, stream>>>(img, conv1_w, conv1_b, conv1out);
    conv2_k<<<B_, 256, 0, stream>>>(conv1out, conv2_w, conv2_b, feat);
    imgfc_gemm<<<dim3(8, 16), 256, 0, stream>>>(feat, imgfc_w, imgfc_b, e);

    lstm_persist<<<256, 512, 64 * 648 * sizeof(unsigned short), stream>>>(
        xbf, wt, cbias, e, hs, ctr);

    logits_mfma<<<(T_ * B_) / 64, 256, 0, stream>>>(hs, wo, out_b, outp);
}